// Round 18
// baseline (234.832 us; speedup 1.0000x reference)
//
#include <hip/hip_runtime.h>
#include <hip/hip_bf16.h>
#include <math.h>

#define S_LEN  2048
#define B_SZ   256
#define T_TAGS 48
#define MAT_U32 1152          // 48 rows * 24 u32 (bf16-packed 48x48)

#define WS_CNT_OFF 0          // 256 ints
#define WS_K_OFF   1024       // up to 8192 ints (ends at 33792)
#define WS_P_OFF   65536      // chunk matrices

using short8 = __attribute__((ext_vector_type(8))) short;
using f32x4  = __attribute__((ext_vector_type(4))) float;
using f32x2  = __attribute__((ext_vector_type(2))) float;

// native exp2 (single v_exp_f32). libm exp2f (ocml, ~8 instrs) was the
// R11-R14 VALU regression.
#if defined(__has_builtin) && __has_builtin(__builtin_amdgcn_exp2f)
#define EXP2N(x) __builtin_amdgcn_exp2f(x)
#else
#define EXP2N(x) __expf((x) * 0.6931471805599453f)
#endif

// single-instruction bf16 pack -- inputs must be compiler VALU results,
// never raw MFMA accumulators (R8/R9 NaN lesson).
__device__ __forceinline__ unsigned cvtpk(float lo, float hi) {
    unsigned r;
    asm("v_cvt_pk_bf16_f32 %0, %1, %2" : "=v"(r) : "v"(lo), "v"(hi));
    return r;
}
// compiler-path bf16 pack (RNE) -- used on raw MFMA outputs (hazards handled)
__device__ __forceinline__ unsigned pk2bf(float lo, float hi) {
    __hip_bfloat162 h2 = __float22bfloat162_rn(make_float2(lo, hi));
    return *reinterpret_cast<unsigned*>(&h2);
}

// ---------------------------------------------------------------------------
// Phase 1: per-chunk transfer matrix P_c (one wave per chunk), CCH=32.
// State Q[n][k] (48x48 bf16, K=48 EXACT -- overlap-K split, no pad) in LDS:
//   region nt (1536 B): addr = nt*1536 + ((k>>3)*16 + (n&15))*16 + (k&7)*2
//   B frag(nt,kt): ds_read_b128 at nt*1536 + kt*512 + tid*16 (contiguous)
//     kt=0 -> k=0..31; kt=1 -> k=16..47 (OVERLAP; A kt=1 zeroes k<32)
//   write frag(jt,nt): ds_write_b64 at nt*1536+((2jt+(g>>1))*16+cc)*16+(g&1)*8
// LDS alloc 5120 B -> 32 blocks/CU. __launch_bounds__(64,5): VGPR budget
// ~102/wave -- R17 showed occupancy stuck at ~12 waves/CU with (64,4)
// (unified-file VGPR+AGPR ~128+/wave); this is the single-variable A/B on
// the register cap. R16's (64,8) forced 32 regs -> catastrophic spill;
// 102 leaves headroom over the ~90-reg working set.
// Renorm probe every 4th step slot; kf consumed once; pend tracks tail.
// Readout: MFMA-transpose (D = Q * I_onehot; ct=0 -> I0, ct>=1 -> I16).
// ---------------------------------------------------------------------------
template<int CCH>
__global__ __launch_bounds__(64, 5) void crf_chunk_kernel(
    const float* __restrict__ em, const int* __restrict__ mask,
    const float* __restrict__ trans, unsigned* __restrict__ wsP,
    int* __restrict__ wsK, int* __restrict__ wsCnt)
{
    constexpr int LCH = S_LEN / CCH;
    constexpr int NQ  = (LCH + 63) / 64;
    const int bid = blockIdx.x;
    const int b = bid / CCH, c = bid % CCH;
    const int tid = threadIdx.x;
    const int cc = tid & 15, g = tid >> 4;
    const int start = c * LCH;

    __shared__ __align__(16) uint4 lds4[320];   // 5120 B (4608 used)
    char* Lc = (char*)lds4;

    // zero, then identity Q[n][n] = 1.0bf16
#pragma unroll
    for (int i = 0; i < 5; ++i) lds4[tid + 64 * i] = make_uint4(0u, 0u, 0u, 0u);
    __builtin_amdgcn_wave_barrier();
    if (tid < T_TAGS)
        *(unsigned short*)(Lc + (tid >> 4) * 1536 +
                           ((tid >> 3) * 16 + (tid & 15)) * 16 + (tid & 7) * 2) = 0x3F80;
    __builtin_amdgcn_wave_barrier();

    // mask ballots + seq-length count
    unsigned long long ball[NQ];
    int cnt = 0;
#pragma unroll
    for (int q = 0; q < NQ; ++q) {
        const int s = start + q * 64 + tid;
        ball[q] = __ballot(mask[s * B_SZ + b] != 0);
        cnt += (int)__popcll(ball[q]);
    }
    if (tid == 0) atomicAdd(&wsCnt[b], cnt);
    if (c == 0) ball[0] &= ~1ull;   // global s=0 is the init, not a transition

    // constant A fragments: A[j][k] = expT[k][j], j = jt*16+cc
    // kt=0: k = 8g+e; kt=1: k = 16+8g+e, ZERO for k<32 (overlap split)
    short8 Afr[3][2];
#pragma unroll
    for (int jt = 0; jt < 3; ++jt) {
        const int j = jt * 16 + cc;
#pragma unroll
        for (int kt = 0; kt < 2; ++kt) {
            unsigned u[4];
#pragma unroll
            for (int h = 0; h < 4; ++h) {
                const int ka = kt * 16 + 8 * g + 2 * h;   // logical k
                const float lo = (kt == 0 || ka >= 32) ? __expf(trans[ka * T_TAGS + j]) : 0.f;
                const float hi = (kt == 0 || ka + 1 >= 32) ? __expf(trans[(ka + 1) * T_TAGS + j]) : 0.f;
                u[h] = cvtpk(lo, hi);
            }
            uint4 uu = make_uint4(u[0], u[1], u[2], u[3]);
            Afr[jt][kt] = *reinterpret_cast<short8*>(&uu);
        }
    }

    int K = 0, pend = 0;
    float kf = 0.0f;                 // forward-folded renorm, log2 units
    const f32x4 fz = {0.f, 0.f, 0.f, 0.f};
    const size_t embase = (size_t)b * T_TAGS + 4 * g;

    auto emload = [&](int t, f32x4& d0, f32x4& d1, f32x4& d2) {
        int ss = start + t; if (ss > S_LEN - 1) ss = S_LEN - 1;
        const float* p = em + (size_t)ss * (B_SZ * T_TAGS) + embase;
        d0 = *(const f32x4*)(p);
        d1 = *(const f32x4*)(p + 16);
        d2 = *(const f32x4*)(p + 32);
    };

    auto step = [&](bool on, bool probe,
                    const f32x4& e0, const f32x4& e1, const f32x4& e2) {
        if (!on) return;
        const short8 B00 = *(const short8*)(Lc +               tid * 16);
        const short8 B01 = *(const short8*)(Lc +         512 + tid * 16);
        const short8 B10 = *(const short8*)(Lc + 1536 +        tid * 16);
        const short8 B11 = *(const short8*)(Lc + 1536 + 512 + tid * 16);
        const short8 B20 = *(const short8*)(Lc + 3072 +        tid * 16);
        const short8 B21 = *(const short8*)(Lc + 3072 + 512 + tid * 16);
        constexpr float L2E = 1.4426950408889634f;
        const float kf_ = kf;
        kf = 0.0f;                    // kf consumed by this step
        pend = 0;                     // last probe's scale now applied
        const f32x2 kf2 = {kf_, kf_};
        const f32x2 l2e2 = {L2E, L2E};
        f32x2 x0a = (f32x2){e0[0], e0[1]} * l2e2 + kf2;
        f32x2 x0b = (f32x2){e0[2], e0[3]} * l2e2 + kf2;
        f32x2 x1a = (f32x2){e1[0], e1[1]} * l2e2 + kf2;
        f32x2 x1b = (f32x2){e1[2], e1[3]} * l2e2 + kf2;
        f32x2 x2a = (f32x2){e2[0], e2[1]} * l2e2 + kf2;
        f32x2 x2b = (f32x2){e2[2], e2[3]} * l2e2 + kf2;
        const f32x2 ef0a = {EXP2N(x0a[0]), EXP2N(x0a[1])};
        const f32x2 ef0b = {EXP2N(x0b[0]), EXP2N(x0b[1])};
        const f32x2 ef1a = {EXP2N(x1a[0]), EXP2N(x1a[1])};
        const f32x2 ef1b = {EXP2N(x1b[0]), EXP2N(x1b[1])};
        const f32x2 ef2a = {EXP2N(x2a[0]), EXP2N(x2a[1])};
        const f32x2 ef2b = {EXP2N(x2b[0]), EXP2N(x2b[1])};
        f32x4 z;
#define DOFRAG(JT, NT, BN0, BN1, EFa, EFb, PROBE_)                             \
        z = __builtin_amdgcn_mfma_f32_16x16x32_bf16(Afr[JT][0], BN0, fz, 0, 0, 0); \
        z = __builtin_amdgcn_mfma_f32_16x16x32_bf16(Afr[JT][1], BN1, z,  0, 0, 0); \
        if (PROBE_) {                                                          \
            const unsigned pb_ = (unsigned)__builtin_amdgcn_readfirstlane(     \
                (int)__float_as_uint(z[0]));                                   \
            const int ee_ = (int)((pb_ >> 23) & 255u);                         \
            const int kk_ = ee_ - 127;                                         \
            K += kk_; pend = kk_;                                              \
            kf = (float)(-kk_);                                                \
        }                                                                      \
        {                                                                      \
            const f32x2 zl_ = (f32x2){z[0], z[1]} * (EFa);                     \
            const f32x2 zh_ = (f32x2){z[2], z[3]} * (EFb);                     \
            *(uint2*)(Lc + (NT) * 1536 +                                       \
                      ((2 * (JT) + (g >> 1)) * 16 + cc) * 16 + (g & 1) * 8) =  \
                make_uint2(cvtpk(zl_[0], zl_[1]), cvtpk(zh_[0], zh_[1]));      \
        }

        DOFRAG(0, 0, B00, B01, ef0a, ef0b, probe);
        DOFRAG(0, 1, B10, B11, ef0a, ef0b, false);
        DOFRAG(0, 2, B20, B21, ef0a, ef0b, false);
        DOFRAG(1, 0, B00, B01, ef1a, ef1b, false);
        DOFRAG(1, 1, B10, B11, ef1a, ef1b, false);
        DOFRAG(1, 2, B20, B21, ef1a, ef1b, false);
        DOFRAG(2, 0, B00, B01, ef2a, ef2b, false);
        DOFRAG(2, 1, B10, B11, ef2a, ef2b, false);
        DOFRAG(2, 2, B20, B21, ef2a, ef2b, false);
#undef DOFRAG
    };

    // 2-deep em software pipeline
    f32x4 a0, a1, a2, b0, b1, b2;
    emload(0, a0, a1, a2);
    emload(1, b0, b1, b2);

#pragma unroll
    for (int q = 0; q < NQ; ++q) {
        const unsigned long long bq = ball[q];
        for (int tt = 0; tt < 64; tt += 2) {
            const int t = q * 64 + tt;
            step(((bq >> tt) & 1ull) != 0, (tt & 3) == 0, a0, a1, a2);
            emload(t + 2, a0, a1, a2);
            step(((bq >> (tt + 1)) & 1ull) != 0, false, b0, b1, b2);
            emload(t + 3, b0, b1, b2);
        }
    }

    // ---- readout via MFMA-transpose: D = Q * I_onehot ----
    // F0 = k 0..31, F1 = k 16..47 (overlap). Column block ct selects
    // logical k = ct*16+cc: ct=0 -> F0,I0; ct=1 -> F0,I16; ct=2 -> F1,I16.
    auto mkI = [&](int shift) -> short8 {
        const int e = cc + shift - 8 * g;
        uint4 uu;
        uu.x = (e == 0) ? 0x3F80u : (e == 1) ? 0x3F800000u : 0u;
        uu.y = (e == 2) ? 0x3F80u : (e == 3) ? 0x3F800000u : 0u;
        uu.z = (e == 4) ? 0x3F80u : (e == 5) ? 0x3F800000u : 0u;
        uu.w = (e == 6) ? 0x3F80u : (e == 7) ? 0x3F800000u : 0u;
        return *reinterpret_cast<short8*>(&uu);
    };
    const short8 I0  = mkI(0);
    const short8 I16 = mkI(16);

    short8 F0[3], F1[3];
#pragma unroll
    for (int nt = 0; nt < 3; ++nt) {
        F0[nt] = *(const short8*)(Lc + nt * 1536 +       tid * 16);
        F1[nt] = *(const short8*)(Lc + nt * 1536 + 512 + tid * 16);
    }
#pragma unroll
    for (int nt = 0; nt < 3; ++nt) {
#pragma unroll
        for (int ct = 0; ct < 3; ++ct) {
            const short8 Af = (ct < 2) ? F0[nt] : F1[nt];
            const short8 Bi = (ct == 0) ? I0 : I16;
            f32x4 z = __builtin_amdgcn_mfma_f32_16x16x32_bf16(Af, Bi, fz, 0, 0, 0);
            // lane(cc,g) reg r holds Q[nt*16+4g+r][ct*16+cc]
            const int jcol = ct * 16 + cc;
            *(uint2*)&wsP[(size_t)bid * MAT_U32 + jcol * 24 + nt * 8 + g * 2] =
                make_uint2(pk2bf(z[0], z[1]), pk2bf(z[2], z[3]));
        }
    }
    if (tid == 0) wsK[bid] = K - pend;
}

// ---------------------------------------------------------------------------
// Phase 2: per-sequence combine over CCH chunk matrices + endT + log,
// PLUS the full numerator (gathers live here -- latency-slack kernel).
// ---------------------------------------------------------------------------
template<int CCH>
__global__ __launch_bounds__(64, 1) void crf_combine_kernel(
    const float* __restrict__ em, const int* __restrict__ mask,
    const float* __restrict__ startT, const float* __restrict__ endT,
    const float* __restrict__ trans, const unsigned* __restrict__ wsP,
    const int* __restrict__ wsK, const int* __restrict__ wsCnt,
    const int* __restrict__ tags, float* __restrict__ out)
{
    const int b = blockIdx.x, tid = threadIdx.x;
    const int j = (tid < T_TAGS) ? tid : 0;

    // ---- numerator gather (independent loads, unrolled) ----
    float nacc = 0.f;
#pragma unroll 4
    for (int q = 0; q < S_LEN / 64; ++q) {
        const int s = q * 64 + tid;
        if (s == 0) {
            const int t0 = tags[b];
            nacc += em[(size_t)b * T_TAGS + t0] + startT[t0];
        } else if (mask[s * B_SZ + b] != 0) {
            const int tc = tags[(size_t)s * B_SZ + b];
            const int tp = tags[(size_t)(s - 1) * B_SZ + b];
            nacc += em[((size_t)s * B_SZ + b) * T_TAGS + tc] + trans[tp * T_TAGS + tc];
        }
    }
#pragma unroll
    for (int off = 32; off > 0; off >>= 1) nacc += __shfl_down(nacc, off);

    // ---- denominator combine ----
    float v = (tid < T_TAGS) ? __expf(startT[j] + em[(size_t)b * T_TAGS + j]) : 0.f;
    int K2 = 0;
    for (int c = 0; c < CCH; ++c) {
        const unsigned base = (unsigned)(b * CCH + c) * MAT_U32 + j * 24;
        uint4 W[6];
#pragma unroll
        for (int q = 0; q < 6; ++q)
            W[q] = *reinterpret_cast<const uint4*>(&wsP[base + 4 * q]);
        float a0 = 0.f, a1 = 0.f;
#pragma unroll
        for (int q = 0; q < 6; ++q) {
            const unsigned wv[4] = {W[q].x, W[q].y, W[q].z, W[q].w};
#pragma unroll
            for (int r = 0; r < 4; ++r) {
                const int i = q * 8 + r * 2;
                const float p0 = __uint_as_float(wv[r] << 16);
                const float p1 = __uint_as_float(wv[r] & 0xFFFF0000u);
                a0 = fmaf(__uint_as_float(__builtin_amdgcn_readlane(__float_as_uint(v), i)), p0, a0);
                a1 = fmaf(__uint_as_float(__builtin_amdgcn_readlane(__float_as_uint(v), i + 1)), p1, a1);
            }
        }
        const float vn = a0 + a1;
        const unsigned pb = (unsigned)__builtin_amdgcn_readfirstlane((int)__float_as_uint(vn));
        const int ee = (int)((pb >> 23) & 255u);
        const float sc = __uint_as_float((unsigned)(254 - ee) << 23);
        v = vn * sc;
        K2 += (ee - 127) + wsK[b * CCH + c];
    }
    float contrib = (tid < T_TAGS) ? v * __expf(endT[j]) : 0.f;
#pragma unroll
    for (int off = 32; off > 0; off >>= 1) contrib += __shfl_down(contrib, off);
    if (tid == 0) {
        const int cnt  = wsCnt[b];
        const int last = tags[(size_t)(cnt - 1) * B_SZ + b];
        const double den = (double)K2 * 0.6931471805599453 + (double)__logf(contrib);
        atomicAdd(out, nacc + endT[last] + (float)(-den));
    }
}

extern "C" void kernel_launch(void* const* d_in, const int* in_sizes, int n_in,
                              void* d_out, int out_size, void* d_ws, size_t ws_size,
                              hipStream_t stream)
{
    const float* em     = (const float*)d_in[0];
    const int*   tags   = (const int*)  d_in[1];
    const int*   mask   = (const int*)  d_in[2];
    const float* startT = (const float*)d_in[3];
    const float* endT   = (const float*)d_in[4];
    const float* trans  = (const float*)d_in[5];
    float* out = (float*)d_out;

    int*      wsCnt = (int*)((char*)d_ws + WS_CNT_OFF);
    int*      wsK   = (int*)((char*)d_ws + WS_K_OFF);
    unsigned* wsP   = (unsigned*)((char*)d_ws + WS_P_OFF);

    hipMemsetAsync(out, 0, sizeof(float), stream);
    hipMemsetAsync(wsCnt, 0, B_SZ * sizeof(int), stream);

    const size_t need32 = (size_t)WS_P_OFF + (size_t)(B_SZ * 32) * (MAT_U32 * 4);
    const size_t need16 = (size_t)WS_P_OFF + (size_t)(B_SZ * 16) * (MAT_U32 * 4);
    if (ws_size >= need32) {
        crf_chunk_kernel<32><<<B_SZ * 32, 64, 0, stream>>>(em, mask, trans, wsP, wsK, wsCnt);
        crf_combine_kernel<32><<<B_SZ, 64, 0, stream>>>(em, mask, startT, endT, trans, wsP, wsK, wsCnt, tags, out);
    } else if (ws_size >= need16) {
        crf_chunk_kernel<16><<<B_SZ * 16, 64, 0, stream>>>(em, mask, trans, wsP, wsK, wsCnt);
        crf_combine_kernel<16><<<B_SZ, 64, 0, stream>>>(em, mask, startT, endT, trans, wsP, wsK, wsCnt, tags, out);
    } else {
        crf_chunk_kernel<8><<<B_SZ * 8, 64, 0, stream>>>(em, mask, trans, wsP, wsK, wsCnt);
        crf_combine_kernel<8><<<B_SZ, 64, 0, stream>>>(em, mask, startT, endT, trans, wsP, wsK, wsCnt, tags, out);
    }
}

// Round 19
// 197.207 us; speedup vs baseline: 1.1908x; 1.1908x over previous
//
#include <hip/hip_runtime.h>
#include <hip/hip_bf16.h>
#include <math.h>

#define S_LEN  2048
#define B_SZ   256
#define T_TAGS 48
#define MAT_U32 1152          // 48 rows * 24 u32 (bf16-packed 48x48)

#define WS_K_OFF   1024       // up to 8192 ints
#define WS_P_OFF   65536      // chunk matrices

using short8 = __attribute__((ext_vector_type(8))) short;
using f32x4  = __attribute__((ext_vector_type(4))) float;
using f32x2  = __attribute__((ext_vector_type(2))) float;

// native exp2 (single v_exp_f32). libm exp2f (ocml, ~8 instrs) was the
// R11-R14 VALU regression.
#if defined(__has_builtin) && __has_builtin(__builtin_amdgcn_exp2f)
#define EXP2N(x) __builtin_amdgcn_exp2f(x)
#else
#define EXP2N(x) __expf((x) * 0.6931471805599453f)
#endif

// single-instruction bf16 pack -- inputs must be compiler VALU results,
// never raw MFMA accumulators (R8/R9 NaN lesson).
__device__ __forceinline__ unsigned cvtpk(float lo, float hi) {
    unsigned r;
    asm("v_cvt_pk_bf16_f32 %0, %1, %2" : "=v"(r) : "v"(lo), "v"(hi));
    return r;
}
// compiler-path bf16 pack (RNE) -- used on raw MFMA outputs (hazards handled)
__device__ __forceinline__ unsigned pk2bf(float lo, float hi) {
    __hip_bfloat162 h2 = __float22bfloat162_rn(make_float2(lo, hi));
    return *reinterpret_cast<unsigned*>(&h2);
}

// ---------------------------------------------------------------------------
// Phase 1: per-chunk transfer matrix P_c (one wave per chunk), CCH=16.
// State Q[n][k] (48x48 bf16, K=48 EXACT -- overlap-K split, no pad) in LDS:
//   region nt (1536 B): addr = nt*1536 + ((k>>3)*16 + (n&15))*16 + (k&7)*2
//   B frag(nt,kt): ds_read_b128 at nt*1536 + kt*512 + tid*16 (contiguous)
//     kt=0 -> k=0..31; kt=1 -> k=16..47 (OVERLAP; A kt=1 zeroes k<32)
//   write frag(jt,nt): ds_write_b64 at nt*1536+((2jt+(g>>1))*16+cc)*16+(g&1)*8
// Issue-port analysis (R15-R18): VALUBusy+MfmaUtil ~84%, occupancy-
// insensitive (33/38/45% all ~190 us) -> SIMD issue saturated; CCH=16
// minimizes per-chunk overhead and ws traffic.
// Renorm probe every 4th step slot; kf consumed once; pend tracks tail.
// Readout: MFMA-transpose (D = Q * I_onehot; ct=0 -> I0, ct>=1 -> I16).
// ---------------------------------------------------------------------------
template<int CCH>
__global__ __launch_bounds__(64, 4) void crf_chunk_kernel(
    const float* __restrict__ em, const int* __restrict__ mask,
    const float* __restrict__ trans, unsigned* __restrict__ wsP,
    int* __restrict__ wsK)
{
    constexpr int LCH = S_LEN / CCH;
    constexpr int NQ  = (LCH + 63) / 64;
    const int bid = blockIdx.x;
    const int b = bid / CCH, c = bid % CCH;
    const int tid = threadIdx.x;
    const int cc = tid & 15, g = tid >> 4;
    const int start = c * LCH;

    __shared__ __align__(16) uint4 lds4[288];   // 4608 B
    char* Lc = (char*)lds4;

    // zero, then identity Q[n][n] = 1.0bf16
#pragma unroll
    for (int i = 0; i < 5; ++i) { const int idx = tid + 64 * i; if (idx < 288) lds4[idx] = make_uint4(0u, 0u, 0u, 0u); }
    __builtin_amdgcn_wave_barrier();
    if (tid < T_TAGS)
        *(unsigned short*)(Lc + (tid >> 4) * 1536 +
                           ((tid >> 3) * 16 + (tid & 15)) * 16 + (tid & 7) * 2) = 0x3F80;
    __builtin_amdgcn_wave_barrier();

    // mask ballots
    unsigned long long ball[NQ];
#pragma unroll
    for (int q = 0; q < NQ; ++q) {
        const int s = start + q * 64 + tid;
        ball[q] = __ballot(mask[s * B_SZ + b] != 0);
    }
    if (c == 0) ball[0] &= ~1ull;   // global s=0 is the init, not a transition

    // constant A fragments: A[j][k] = expT[k][j], j = jt*16+cc
    // kt=0: k = 8g+e; kt=1: k = 16+8g+e, ZERO for k<32 (overlap split)
    short8 Afr[3][2];
#pragma unroll
    for (int jt = 0; jt < 3; ++jt) {
        const int j = jt * 16 + cc;
#pragma unroll
        for (int kt = 0; kt < 2; ++kt) {
            unsigned u[4];
#pragma unroll
            for (int h = 0; h < 4; ++h) {
                const int ka = kt * 16 + 8 * g + 2 * h;   // logical k
                const float lo = (kt == 0 || ka >= 32) ? __expf(trans[ka * T_TAGS + j]) : 0.f;
                const float hi = (kt == 0 || ka + 1 >= 32) ? __expf(trans[(ka + 1) * T_TAGS + j]) : 0.f;
                u[h] = cvtpk(lo, hi);
            }
            uint4 uu = make_uint4(u[0], u[1], u[2], u[3]);
            Afr[jt][kt] = *reinterpret_cast<short8*>(&uu);
        }
    }

    int K = 0, pend = 0;
    float kf = 0.0f;                 // forward-folded renorm, log2 units
    const f32x4 fz = {0.f, 0.f, 0.f, 0.f};
    const size_t embase = (size_t)b * T_TAGS + 4 * g;

    auto emload = [&](int t, f32x4& d0, f32x4& d1, f32x4& d2) {
        int ss = start + t; if (ss > S_LEN - 1) ss = S_LEN - 1;
        const float* p = em + (size_t)ss * (B_SZ * T_TAGS) + embase;
        d0 = *(const f32x4*)(p);
        d1 = *(const f32x4*)(p + 16);
        d2 = *(const f32x4*)(p + 32);
    };

    auto step = [&](bool on, bool probe,
                    const f32x4& e0, const f32x4& e1, const f32x4& e2) {
        if (!on) return;
        const short8 B00 = *(const short8*)(Lc +               tid * 16);
        const short8 B01 = *(const short8*)(Lc +         512 + tid * 16);
        const short8 B10 = *(const short8*)(Lc + 1536 +        tid * 16);
        const short8 B11 = *(const short8*)(Lc + 1536 + 512 + tid * 16);
        const short8 B20 = *(const short8*)(Lc + 3072 +        tid * 16);
        const short8 B21 = *(const short8*)(Lc + 3072 + 512 + tid * 16);
        constexpr float L2E = 1.4426950408889634f;
        const float kf_ = kf;
        kf = 0.0f;                    // kf consumed by this step
        pend = 0;                     // last probe's scale now applied
        const f32x2 kf2 = {kf_, kf_};
        const f32x2 l2e2 = {L2E, L2E};
        f32x2 x0a = (f32x2){e0[0], e0[1]} * l2e2 + kf2;
        f32x2 x0b = (f32x2){e0[2], e0[3]} * l2e2 + kf2;
        f32x2 x1a = (f32x2){e1[0], e1[1]} * l2e2 + kf2;
        f32x2 x1b = (f32x2){e1[2], e1[3]} * l2e2 + kf2;
        f32x2 x2a = (f32x2){e2[0], e2[1]} * l2e2 + kf2;
        f32x2 x2b = (f32x2){e2[2], e2[3]} * l2e2 + kf2;
        const f32x2 ef0a = {EXP2N(x0a[0]), EXP2N(x0a[1])};
        const f32x2 ef0b = {EXP2N(x0b[0]), EXP2N(x0b[1])};
        const f32x2 ef1a = {EXP2N(x1a[0]), EXP2N(x1a[1])};
        const f32x2 ef1b = {EXP2N(x1b[0]), EXP2N(x1b[1])};
        const f32x2 ef2a = {EXP2N(x2a[0]), EXP2N(x2a[1])};
        const f32x2 ef2b = {EXP2N(x2b[0]), EXP2N(x2b[1])};
        f32x4 z;
#define DOFRAG(JT, NT, BN0, BN1, EFa, EFb, PROBE_)                             \
        z = __builtin_amdgcn_mfma_f32_16x16x32_bf16(Afr[JT][0], BN0, fz, 0, 0, 0); \
        z = __builtin_amdgcn_mfma_f32_16x16x32_bf16(Afr[JT][1], BN1, z,  0, 0, 0); \
        if (PROBE_) {                                                          \
            const unsigned pb_ = (unsigned)__builtin_amdgcn_readfirstlane(     \
                (int)__float_as_uint(z[0]));                                   \
            const int ee_ = (int)((pb_ >> 23) & 255u);                         \
            const int kk_ = ee_ - 127;                                         \
            K += kk_; pend = kk_;                                              \
            kf = (float)(-kk_);                                                \
        }                                                                      \
        {                                                                      \
            const f32x2 zl_ = (f32x2){z[0], z[1]} * (EFa);                     \
            const f32x2 zh_ = (f32x2){z[2], z[3]} * (EFb);                     \
            *(uint2*)(Lc + (NT) * 1536 +                                       \
                      ((2 * (JT) + (g >> 1)) * 16 + cc) * 16 + (g & 1) * 8) =  \
                make_uint2(cvtpk(zl_[0], zl_[1]), cvtpk(zh_[0], zh_[1]));      \
        }

        DOFRAG(0, 0, B00, B01, ef0a, ef0b, probe);
        DOFRAG(0, 1, B10, B11, ef0a, ef0b, false);
        DOFRAG(0, 2, B20, B21, ef0a, ef0b, false);
        DOFRAG(1, 0, B00, B01, ef1a, ef1b, false);
        DOFRAG(1, 1, B10, B11, ef1a, ef1b, false);
        DOFRAG(1, 2, B20, B21, ef1a, ef1b, false);
        DOFRAG(2, 0, B00, B01, ef2a, ef2b, false);
        DOFRAG(2, 1, B10, B11, ef2a, ef2b, false);
        DOFRAG(2, 2, B20, B21, ef2a, ef2b, false);
#undef DOFRAG
    };

    // 2-deep em software pipeline
    f32x4 a0, a1, a2, b0, b1, b2;
    emload(0, a0, a1, a2);
    emload(1, b0, b1, b2);

#pragma unroll
    for (int q = 0; q < NQ; ++q) {
        const unsigned long long bq = ball[q];
        for (int tt = 0; tt < 64; tt += 2) {
            const int t = q * 64 + tt;
            step(((bq >> tt) & 1ull) != 0, (tt & 3) == 0, a0, a1, a2);
            emload(t + 2, a0, a1, a2);
            step(((bq >> (tt + 1)) & 1ull) != 0, false, b0, b1, b2);
            emload(t + 3, b0, b1, b2);
        }
    }

    // ---- readout via MFMA-transpose: D = Q * I_onehot ----
    // F0 = k 0..31, F1 = k 16..47 (overlap). Column block ct selects
    // logical k = ct*16+cc: ct=0 -> F0,I0; ct=1 -> F0,I16; ct=2 -> F1,I16.
    auto mkI = [&](int shift) -> short8 {
        const int e = cc + shift - 8 * g;
        uint4 uu;
        uu.x = (e == 0) ? 0x3F80u : (e == 1) ? 0x3F800000u : 0u;
        uu.y = (e == 2) ? 0x3F80u : (e == 3) ? 0x3F800000u : 0u;
        uu.z = (e == 4) ? 0x3F80u : (e == 5) ? 0x3F800000u : 0u;
        uu.w = (e == 6) ? 0x3F80u : (e == 7) ? 0x3F800000u : 0u;
        return *reinterpret_cast<short8*>(&uu);
    };
    const short8 I0  = mkI(0);
    const short8 I16 = mkI(16);

    short8 F0[3], F1[3];
#pragma unroll
    for (int nt = 0; nt < 3; ++nt) {
        F0[nt] = *(const short8*)(Lc + nt * 1536 +       tid * 16);
        F1[nt] = *(const short8*)(Lc + nt * 1536 + 512 + tid * 16);
    }
#pragma unroll
    for (int nt = 0; nt < 3; ++nt) {
#pragma unroll
        for (int ct = 0; ct < 3; ++ct) {
            const short8 Af = (ct < 2) ? F0[nt] : F1[nt];
            const short8 Bi = (ct == 0) ? I0 : I16;
            f32x4 z = __builtin_amdgcn_mfma_f32_16x16x32_bf16(Af, Bi, fz, 0, 0, 0);
            // lane(cc,g) reg r holds Q[nt*16+4g+r][ct*16+cc]
            const int jcol = ct * 16 + cc;
            *(uint2*)&wsP[(size_t)bid * MAT_U32 + jcol * 24 + nt * 8 + g * 2] =
                make_uint2(pk2bf(z[0], z[1]), pk2bf(z[2], z[3]));
        }
    }
    if (tid == 0) wsK[bid] = K - pend;
}

// ---------------------------------------------------------------------------
// Phase 2 (256 threads): numerator gather split across 4 waves (8 serial
// rounds each instead of 32), block-reduce in LDS; wave 0 then does the
// denominator combine over CCH chunk matrices + endT + log.
// Seq-length count also computed here (wsCnt atomic removed from phase 1).
// ---------------------------------------------------------------------------
template<int CCH>
__global__ __launch_bounds__(256, 1) void crf_combine_kernel(
    const float* __restrict__ em, const int* __restrict__ mask,
    const float* __restrict__ startT, const float* __restrict__ endT,
    const float* __restrict__ trans, const unsigned* __restrict__ wsP,
    const int* __restrict__ wsK, const int* __restrict__ tags,
    float* __restrict__ out)
{
    const int b = blockIdx.x, tid = threadIdx.x;
    const int lane = tid & 63, wid = tid >> 6;

    __shared__ float s_nacc[4];
    __shared__ int   s_cnt[4];

    // ---- numerator gather + mask count (4 waves in parallel) ----
    float nacc = 0.f;
    int cnt = 0;
    for (int q = wid; q < S_LEN / 64; q += 4) {
        const int s = q * 64 + lane;
        const int mk = mask[s * B_SZ + b];
        cnt += (mk != 0);
        if (s == 0) {
            const int t0 = tags[b];
            nacc += em[(size_t)b * T_TAGS + t0] + startT[t0];
        } else if (mk != 0) {
            const int tc = tags[(size_t)s * B_SZ + b];
            const int tp = tags[(size_t)(s - 1) * B_SZ + b];
            nacc += em[((size_t)s * B_SZ + b) * T_TAGS + tc] + trans[tp * T_TAGS + tc];
        }
    }
#pragma unroll
    for (int off = 32; off > 0; off >>= 1) {
        nacc += __shfl_down(nacc, off);
        cnt  += __shfl_down(cnt, off);
    }
    if (lane == 0) { s_nacc[wid] = nacc; s_cnt[wid] = cnt; }
    __syncthreads();
    if (tid >= 64) return;

    const float nall = s_nacc[0] + s_nacc[1] + s_nacc[2] + s_nacc[3];
    const int   call = s_cnt[0] + s_cnt[1] + s_cnt[2] + s_cnt[3];

    // ---- denominator combine (wave 0 only) ----
    const int j = (lane < T_TAGS) ? lane : 0;
    float v = (lane < T_TAGS) ? __expf(startT[j] + em[(size_t)b * T_TAGS + j]) : 0.f;
    int K2 = 0;
    for (int c = 0; c < CCH; ++c) {
        const unsigned base = (unsigned)(b * CCH + c) * MAT_U32 + j * 24;
        uint4 W[6];
#pragma unroll
        for (int q = 0; q < 6; ++q)
            W[q] = *reinterpret_cast<const uint4*>(&wsP[base + 4 * q]);
        float a0 = 0.f, a1 = 0.f;
#pragma unroll
        for (int q = 0; q < 6; ++q) {
            const unsigned wv[4] = {W[q].x, W[q].y, W[q].z, W[q].w};
#pragma unroll
            for (int r = 0; r < 4; ++r) {
                const int i = q * 8 + r * 2;
                const float p0 = __uint_as_float(wv[r] << 16);
                const float p1 = __uint_as_float(wv[r] & 0xFFFF0000u);
                a0 = fmaf(__uint_as_float(__builtin_amdgcn_readlane(__float_as_uint(v), i)), p0, a0);
                a1 = fmaf(__uint_as_float(__builtin_amdgcn_readlane(__float_as_uint(v), i + 1)), p1, a1);
            }
        }
        const float vn = a0 + a1;
        const unsigned pb = (unsigned)__builtin_amdgcn_readfirstlane((int)__float_as_uint(vn));
        const int ee = (int)((pb >> 23) & 255u);
        const float sc = __uint_as_float((unsigned)(254 - ee) << 23);
        v = vn * sc;
        K2 += (ee - 127) + wsK[b * CCH + c];
    }
    float contrib = (lane < T_TAGS) ? v * __expf(endT[j]) : 0.f;
#pragma unroll
    for (int off = 32; off > 0; off >>= 1) contrib += __shfl_down(contrib, off);
    if (lane == 0) {
        const int last = tags[(size_t)(call - 1) * B_SZ + b];
        const double den = (double)K2 * 0.6931471805599453 + (double)__logf(contrib);
        atomicAdd(out, nall + endT[last] + (float)(-den));
    }
}

extern "C" void kernel_launch(void* const* d_in, const int* in_sizes, int n_in,
                              void* d_out, int out_size, void* d_ws, size_t ws_size,
                              hipStream_t stream)
{
    const float* em     = (const float*)d_in[0];
    const int*   tags   = (const int*)  d_in[1];
    const int*   mask   = (const int*)  d_in[2];
    const float* startT = (const float*)d_in[3];
    const float* endT   = (const float*)d_in[4];
    const float* trans  = (const float*)d_in[5];
    float* out = (float*)d_out;

    int*      wsK = (int*)((char*)d_ws + WS_K_OFF);
    unsigned* wsP = (unsigned*)((char*)d_ws + WS_P_OFF);

    hipMemsetAsync(out, 0, sizeof(float), stream);

    const size_t need16 = (size_t)WS_P_OFF + (size_t)(B_SZ * 16) * (MAT_U32 * 4);
    if (ws_size >= need16) {
        crf_chunk_kernel<16><<<B_SZ * 16, 64, 0, stream>>>(em, mask, trans, wsP, wsK);
        crf_combine_kernel<16><<<B_SZ, 256, 0, stream>>>(em, mask, startT, endT, trans, wsP, wsK, tags, out);
    } else {
        crf_chunk_kernel<8><<<B_SZ * 8, 64, 0, stream>>>(em, mask, trans, wsP, wsK);
        crf_combine_kernel<8><<<B_SZ, 256, 0, stream>>>(em, mask, startT, endT, trans, wsP, wsK, tags, out);
    }
}